// Round 1
// baseline (416.375 us; speedup 1.0000x reference)
//
#include <hip/hip_runtime.h>
#include <hip/hip_bf16.h>

#define HSIZE   (1 << 20)
#define HMASK   (HSIZE - 1)
#define PAIR_CAP (1 << 18)

typedef __bf16 bf16_t;
typedef bf16_t bf16x8 __attribute__((ext_vector_type(8)));
typedef float  f32x4  __attribute__((ext_vector_type(4)));

__device__ __forceinline__ unsigned hash_key(int k) {
    return ((unsigned)k * 2654435761u) >> 12;   // top 20 bits -> [0, 2^20)
}

// K1: pack coord keys + 4096-bucket histogram (bucket = key >> 18)
__global__ void k_keys_hist(const int* __restrict__ coords, int* __restrict__ keys,
                            int* __restrict__ hist, int N) {
    int i = blockIdx.x * blockDim.x + threadIdx.x;
    if (i >= N) return;
    int c0 = coords[3 * i], c1 = coords[3 * i + 1], c2 = coords[3 * i + 2];
    int key = (c0 << 20) | (c1 << 10) | c2;
    keys[i] = key;
    atomicAdd(&hist[key >> 18], 1);
}

// K2: exclusive prefix over 4096 buckets (1 block, 256 threads x 16-wide segments)
__global__ void k_prefix(const int* __restrict__ hist, int* __restrict__ base) {
    __shared__ int part[256];
    int t = threadIdx.x;
    int vals[16];
    int s = 0;
#pragma unroll
    for (int j = 0; j < 16; ++j) { vals[j] = hist[t * 16 + j]; s += vals[j]; }
    part[t] = s;
    __syncthreads();
    if (t == 0) {
        int run = 0;
        for (int u = 0; u < 256; ++u) { int tmp = part[u]; part[u] = run; run += tmp; }
    }
    __syncthreads();
    int run = part[t];
#pragma unroll
    for (int j = 0; j < 16; ++j) { base[t * 16 + j] = run; run += vals[j]; }
    if (t == 255) base[4096] = run;   // == N
}

// K3: scatter into buckets (unsorted within bucket)
__global__ void k_scatter(const int* __restrict__ keys, const int* __restrict__ base,
                          int* __restrict__ cnt, int* __restrict__ bkeys,
                          int* __restrict__ borig, int N) {
    int i = blockIdx.x * blockDim.x + threadIdx.x;
    if (i >= N) return;
    int key = keys[i];
    int b = key >> 18;
    int pos = base[b] + atomicAdd(&cnt[b], 1);
    bkeys[pos] = key;
    borig[pos] = i;
}

// K4: per-bucket rank sort (keys unique -> rank = #smaller). avg bucket ~98.
__global__ void k_bucket_sort(const int* __restrict__ base, const int* __restrict__ bkeys,
                              const int* __restrict__ borig, int* __restrict__ skeys,
                              int* __restrict__ sorder) {
    int b = blockIdx.x;
    int lo = base[b], hi = base[b + 1];
    int size = hi - lo;
    if (size <= 0) return;
    __shared__ int sk[1024];
    for (int e = threadIdx.x; e < size && e < 1024; e += 256) sk[e] = bkeys[lo + e];
    __syncthreads();
    for (int e = threadIdx.x; e < size; e += 256) {
        int myk = (e < 1024) ? sk[e] : bkeys[lo + e];
        int r = 0;
        for (int j = 0; j < size; ++j) {
            int kj = (j < 1024) ? sk[j] : bkeys[lo + j];
            r += (kj < myk);
        }
        skeys[lo + r] = myk;
        sorder[lo + r] = borig[lo + e];
    }
}

// K5: hash insert skeys[i] -> i  (slots pre-set to -1 via memset 0xFF)
__global__ void k_hash_insert(const int* __restrict__ skeys, int* __restrict__ hkeys,
                              int* __restrict__ hvals, int N) {
    int i = blockIdx.x * blockDim.x + threadIdx.x;
    if (i >= N) return;
    int key = skeys[i];
    unsigned slot = hash_key(key);
    for (;;) {
        int old = atomicCAS(&hkeys[slot], -1, key);
        if (old == -1) { hvals[slot] = i; break; }
        slot = (slot + 1) & HMASK;
    }
}

// K6: query 13 half-offsets per point; each match emits (i<-j,k) and mirror (j<-i,26-k)
__global__ void k_query(const int* __restrict__ skeys, const int* __restrict__ sorder,
                        const int* __restrict__ offs, const int* __restrict__ hkeys,
                        const int* __restrict__ hvals, int* __restrict__ paircnt,
                        int* __restrict__ pairs, int N) {
    long long t = (long long)blockIdx.x * blockDim.x + threadIdx.x;
    if (t >= 13LL * N) return;
    int i = (int)(t % N);
    int k = (int)(t / N);          // 0..12, center (13) handled densely
    int ox = offs[3 * k], oy = offs[3 * k + 1], oz = offs[3 * k + 2];
    int okey = ox * 1048576 + oy * 1024 + oz;
    int qk = skeys[i] + okey;
    unsigned slot = hash_key(qk);
    int j = -1;
    for (;;) {
        int kk = hkeys[slot];
        if (kk == qk) { j = hvals[slot]; break; }
        if (kk == -1) break;
        slot = (slot + 1) & HMASK;
    }
    if (j < 0) return;
    int idx = atomicAdd(paircnt, 2);
    if (idx + 1 < PAIR_CAP) {
        // out[i] += F[sorder[j]] @ W[k];  out[j] += F[sorder[i]] @ W[26-k]
        pairs[3 * idx + 0] = i;
        pairs[3 * idx + 1] = sorder[j];
        pairs[3 * idx + 2] = k;
        pairs[3 * idx + 3] = j;
        pairs[3 * idx + 4] = sorder[i];
        pairs[3 * idx + 5] = 26 - k;
    }
}

// K0: pre-pack W[13] (center) into bf16 MFMA B-fragment order.
// frag f = nt*2+kt (nt 0..3, kt 0..1); elem (lane l, j): B[k][n],
// k = kt*32 + (l>>4)*8 + j, n = nt*16 + (l&15). wf[f*512 + l*8 + j].
__global__ void k_wfrag(const float* __restrict__ kern, bf16_t* __restrict__ wf) {
    int tid = blockIdx.x * blockDim.x + threadIdx.x;
    if (tid >= 4096) return;
    int f = tid >> 9, l = (tid >> 3) & 63, j = tid & 7;
    int nt = f >> 1, kt = f & 1;
    int k = kt * 32 + ((l >> 4) * 8) + j;
    int n = nt * 16 + (l & 15);
    wf[tid] = (bf16_t)kern[13 * 4096 + k * 64 + n];
}

// K7: dense center GEMM  out[i] = F[sorder[i]] @ W13, MFMA 16x16x32 bf16, no LDS.
// Wave handles 16 rows; block = 4 waves = 64 rows.
__global__ __launch_bounds__(256) void k_gemm(const float* __restrict__ feat,
                                              const bf16_t* __restrict__ wf,
                                              const int* __restrict__ sorder,
                                              float* __restrict__ out, int N) {
    const int lane = threadIdx.x & 63;
    const int wv = threadIdx.x >> 6;
    const int m = lane & 15, quad = lane >> 4;
    const int tile = blockIdx.x * 64 + wv * 16;
    int row = tile + m;
    if (row >= N) row = N - 1;
    const int orig = sorder[row];
    const float* rp = feat + (size_t)orig * 64;
    bf16x8 a[2];
#pragma unroll
    for (int kt = 0; kt < 2; ++kt) {
        const float* p = rp + kt * 32 + quad * 8;
        float4 x = *(const float4*)p;
        float4 y = *(const float4*)(p + 4);
        bf16x8 v;
        v[0] = (bf16_t)x.x; v[1] = (bf16_t)x.y; v[2] = (bf16_t)x.z; v[3] = (bf16_t)x.w;
        v[4] = (bf16_t)y.x; v[5] = (bf16_t)y.y; v[6] = (bf16_t)y.z; v[7] = (bf16_t)y.w;
        a[kt] = v;
    }
#pragma unroll
    for (int nt = 0; nt < 4; ++nt) {
        f32x4 acc = {0.f, 0.f, 0.f, 0.f};
#pragma unroll
        for (int kt = 0; kt < 2; ++kt) {
            bf16x8 bfr = *(const bf16x8*)(wf + ((nt * 2 + kt) * 64 + lane) * 8);
            acc = __builtin_amdgcn_mfma_f32_16x16x32_bf16(a[kt], bfr, acc, 0, 0, 0);
        }
#pragma unroll
        for (int r = 0; r < 4; ++r) {
            int orow = tile + quad * 4 + r;
            if (orow < N) out[(size_t)orow * 64 + nt * 16 + m] = acc[r];
        }
    }
}

// K8: sparse pairs — one wave per pair, fp32 shuffle-dot, atomic accumulate.
__global__ void k_pairs(const float* __restrict__ feat, const float* __restrict__ kern,
                        const int* __restrict__ pairs, const int* __restrict__ paircnt,
                        float* __restrict__ out) {
    int gtid = blockIdx.x * blockDim.x + threadIdx.x;
    int wid = gtid >> 6, lane = gtid & 63;
    int nw = (gridDim.x * blockDim.x) >> 6;
    int cnt = *paircnt;
    if (cnt > PAIR_CAP) cnt = PAIR_CAP;
    for (int p = wid; p < cnt; p += nw) {
        int dst = pairs[3 * p], src = pairs[3 * p + 1], wk = pairs[3 * p + 2];
        float f = feat[(size_t)src * 64 + lane];
        const float* W = kern + wk * 4096;
        float acc = 0.f;
#pragma unroll
        for (int c = 0; c < 64; ++c)
            acc += __shfl(f, c, 64) * W[c * 64 + lane];
        atomicAdd(&out[(size_t)dst * 64 + lane], acc);
    }
}

extern "C" void kernel_launch(void* const* d_in, const int* in_sizes, int n_in,
                              void* d_out, int out_size, void* d_ws, size_t ws_size,
                              hipStream_t stream) {
    const float* feat   = (const float*)d_in[0];
    const float* kern   = (const float*)d_in[1];
    const int*   coords = (const int*)d_in[2];
    const int*   offs   = (const int*)d_in[3];
    float* out = (float*)d_out;
    int N = in_sizes[0] / 64;

    // ---- workspace layout (256B-aligned slabs) ----
    char* w = (char*)d_ws;
    auto alloc = [&](size_t bytes) { char* p = w; w += (bytes + 255) & ~(size_t)255; return p; };
    int* keys    = (int*)alloc((size_t)N * 4);
    int* bkeys   = (int*)alloc((size_t)N * 4);
    int* borig   = (int*)alloc((size_t)N * 4);
    int* skeys   = (int*)alloc((size_t)N * 4);
    int* sorder  = (int*)alloc((size_t)N * 4);
    int* hist    = (int*)alloc(4096 * 4);        // contiguous: hist, cnt, paircnt
    int* cnt     = (int*)alloc(4096 * 4);
    int* paircnt = (int*)alloc(256);
    int* base    = (int*)alloc(4097 * 4);
    int* hkeys   = (int*)alloc((size_t)HSIZE * 4);
    int* hvals   = (int*)alloc((size_t)HSIZE * 4);
    int* pairs   = (int*)alloc((size_t)PAIR_CAP * 12);
    bf16_t* wf   = (bf16_t*)alloc(4096 * 2);

    // zero hist+cnt+paircnt (contiguous, each slab 256B-padded), hash keys -> -1
    hipMemsetAsync(hist, 0, 4096 * 4 + 4096 * 4 + 256, stream);
    hipMemsetAsync(hkeys, 0xFF, (size_t)HSIZE * 4, stream);

    int nb = (N + 255) / 256;
    k_keys_hist  <<<nb, 256, 0, stream>>>(coords, keys, hist, N);
    k_prefix     <<<1, 256, 0, stream>>>(hist, base);
    k_scatter    <<<nb, 256, 0, stream>>>(keys, base, cnt, bkeys, borig, N);
    k_bucket_sort<<<4096, 256, 0, stream>>>(base, bkeys, borig, skeys, sorder);
    k_hash_insert<<<nb, 256, 0, stream>>>(skeys, hkeys, hvals, N);
    k_wfrag      <<<16, 256, 0, stream>>>(kern, wf);
    long long nq = 13LL * N;
    k_query      <<<(int)((nq + 255) / 256), 256, 0, stream>>>(skeys, sorder, offs, hkeys,
                                                               hvals, paircnt, pairs, N);
    k_gemm       <<<(N + 63) / 64, 256, 0, stream>>>(feat, wf, sorder, out, N);
    k_pairs      <<<256, 256, 0, stream>>>(feat, kern, pairs, paircnt, out);
}

// Round 2
// 415.700 us; speedup vs baseline: 1.0016x; 1.0016x over previous
//
#include <hip/hip_runtime.h>
#include <hip/hip_bf16.h>

#define HSIZE   (1 << 20)
#define HMASK   (HSIZE - 1)
#define PAIR_CAP (1 << 18)

typedef __bf16 bf16_t;
typedef bf16_t bf16x8 __attribute__((ext_vector_type(8)));
typedef float  f32x4  __attribute__((ext_vector_type(4)));

__device__ __forceinline__ unsigned hash_key(int k) {
    return ((unsigned)k * 2654435761u) >> 12;   // top 20 bits -> [0, 2^20)
}

// K1: pack keys + histogram; tail blocks pre-pack W[13] into MFMA B-frag order.
__global__ void k_phase1(const int* __restrict__ coords, const float* __restrict__ kern,
                         int* __restrict__ keys, int* __restrict__ hist,
                         bf16_t* __restrict__ wf, int N, int nb) {
    if (blockIdx.x >= nb) {
        // W-fragment pack: frag f = nt*2+kt; elem (lane l, j) = B[k][n],
        // k = kt*32+(l>>4)*8+j, n = nt*16+(l&15)
        int tid = (blockIdx.x - nb) * 256 + threadIdx.x;   // 0..4095
        int f = tid >> 9, l = (tid >> 3) & 63, j = tid & 7;
        int nt = f >> 1, kt = f & 1;
        int k = kt * 32 + ((l >> 4) * 8) + j;
        int n = nt * 16 + (l & 15);
        wf[tid] = (bf16_t)kern[13 * 4096 + k * 64 + n];
        return;
    }
    int i = blockIdx.x * 256 + threadIdx.x;
    if (i >= N) return;
    int key = (coords[3 * i] << 20) | (coords[3 * i + 1] << 10) | coords[3 * i + 2];
    keys[i] = key;
    atomicAdd(&hist[key >> 18], 1);
}

// K2: exclusive prefix over 4096 buckets — wave-shuffle scan, 1 block.
__global__ void k_prefix(const int* __restrict__ hist, int* __restrict__ base) {
    int t = threadIdx.x;
    int vals[16];
    int s = 0;
#pragma unroll
    for (int j = 0; j < 16; ++j) { vals[j] = hist[t * 16 + j]; s += vals[j]; }
    int lane = t & 63, wv = t >> 6;
    int x = s;
#pragma unroll
    for (int d = 1; d < 64; d <<= 1) {
        int y = __shfl_up(x, d, 64);
        if (lane >= d) x += y;
    }
    __shared__ int wsum[4];
    if (lane == 63) wsum[wv] = x;
    __syncthreads();
    int add = 0;
    for (int u = 0; u < wv; ++u) add += wsum[u];
    int run = (x + add) - s;                 // exclusive prefix of this thread's segment
#pragma unroll
    for (int j = 0; j < 16; ++j) { base[t * 16 + j] = run; run += vals[j]; }
    if (t == 255) base[4096] = x + add;      // == N
}

// K3: scatter into buckets + hash-insert (key -> original index), fused.
__global__ void k_build(const int* __restrict__ keys, const int* __restrict__ base,
                        int* __restrict__ cnt, int* __restrict__ bkeys,
                        int* __restrict__ borig, int* __restrict__ hkeys,
                        int* __restrict__ hvals, int N) {
    int i = blockIdx.x * 256 + threadIdx.x;
    if (i >= N) return;
    int key = keys[i];
    int b = key >> 18;
    int pos = base[b] + atomicAdd(&cnt[b], 1);
    bkeys[pos] = key;
    borig[pos] = i;
    unsigned slot = hash_key(key);
    for (;;) {
        int old = atomicCAS(&hkeys[slot], -1, key);
        if (old == -1) { hvals[slot] = i; break; }
        slot = (slot + 1) & HMASK;
    }
}

// K4: per-bucket rank sort -> sorder (sorted pos -> orig idx), rank (orig idx -> sorted pos)
__global__ void k_sortrank(const int* __restrict__ base, const int* __restrict__ bkeys,
                           const int* __restrict__ borig, int* __restrict__ sorder,
                           int* __restrict__ rank_) {
    int b = blockIdx.x;
    int lo = base[b], hi = base[b + 1];
    int size = hi - lo;
    if (size <= 0) return;
    __shared__ int sk[512];                  // mean bucket ~98; P(>512) ~ 0
    for (int e = threadIdx.x; e < size && e < 512; e += 256) sk[e] = bkeys[lo + e];
    __syncthreads();
    for (int e = threadIdx.x; e < size; e += 256) {
        int myk = (e < 512) ? sk[e] : bkeys[lo + e];
        int r = 0;
        for (int j = 0; j < size; ++j) {
            int kj = (j < 512) ? sk[j] : bkeys[lo + j];
            r += (kj < myk);
        }
        int o = borig[lo + e];
        sorder[lo + r] = o;
        rank_[o] = lo + r;
    }
}

// K5: dense center GEMM  out[i] = F[sorder[i]] @ W13, MFMA 16x16x32 bf16, no LDS.
__global__ __launch_bounds__(256) void k_gemm(const float* __restrict__ feat,
                                              const bf16_t* __restrict__ wf,
                                              const int* __restrict__ sorder,
                                              float* __restrict__ out, int N) {
    const int lane = threadIdx.x & 63;
    const int wv = threadIdx.x >> 6;
    const int m = lane & 15, quad = lane >> 4;
    const int tile = blockIdx.x * 64 + wv * 16;
    int row = tile + m;
    if (row >= N) row = N - 1;
    const int orig = sorder[row];
    const float* rp = feat + (size_t)orig * 64;
    bf16x8 a[2];
#pragma unroll
    for (int kt = 0; kt < 2; ++kt) {
        const float* p = rp + kt * 32 + quad * 8;
        float4 x = *(const float4*)p;
        float4 y = *(const float4*)(p + 4);
        bf16x8 v;
        v[0] = (bf16_t)x.x; v[1] = (bf16_t)x.y; v[2] = (bf16_t)x.z; v[3] = (bf16_t)x.w;
        v[4] = (bf16_t)y.x; v[5] = (bf16_t)y.y; v[6] = (bf16_t)y.z; v[7] = (bf16_t)y.w;
        a[kt] = v;
    }
#pragma unroll
    for (int nt = 0; nt < 4; ++nt) {
        f32x4 acc = {0.f, 0.f, 0.f, 0.f};
#pragma unroll
        for (int kt = 0; kt < 2; ++kt) {
            bf16x8 bfr = *(const bf16x8*)(wf + ((nt * 2 + kt) * 64 + lane) * 8);
            acc = __builtin_amdgcn_mfma_f32_16x16x32_bf16(a[kt], bfr, acc, 0, 0, 0);
        }
#pragma unroll
        for (int r = 0; r < 4; ++r) {
            int orow = tile + quad * 4 + r;
            if (orow < N) out[(size_t)orow * 64 + nt * 16 + m] = acc[r];
        }
    }
}

// K6: one thread per point; 13 INDEPENDENT first-probe loads (MLP), resolve after.
__global__ void k_query(const int* __restrict__ keys, const int* __restrict__ rank_,
                        const int* __restrict__ offs, const int* __restrict__ hkeys,
                        const int* __restrict__ hvals, int* __restrict__ paircnt,
                        int* __restrict__ pairs, int N) {
    int i = blockIdx.x * 256 + threadIdx.x;
    if (i >= N) return;
    int mykey = keys[i];
    int qk[13], kk[13];
#pragma unroll
    for (int k = 0; k < 13; ++k) {
        int okey = offs[3 * k] * 1048576 + offs[3 * k + 1] * 1024 + offs[3 * k + 2];
        qk[k] = mykey + okey;
    }
#pragma unroll
    for (int k = 0; k < 13; ++k)
        kk[k] = hkeys[hash_key(qk[k])];      // independent loads -> overlapped
#pragma unroll
    for (int k = 0; k < 13; ++k) {
        int j = -1;
        if (kk[k] == qk[k]) {
            j = hvals[hash_key(qk[k])];
        } else if (kk[k] != -1) {            // rare: continue the probe chain
            unsigned slot = (hash_key(qk[k]) + 1) & HMASK;
            for (;;) {
                int t = hkeys[slot];
                if (t == qk[k]) { j = hvals[slot]; break; }
                if (t == -1) break;
                slot = (slot + 1) & HMASK;
            }
        }
        if (j >= 0) {
            int idx = atomicAdd(paircnt, 2);
            if (idx + 1 < PAIR_CAP) {
                // out[rank(i)] += F[j] @ W[k];  out[rank(j)] += F[i] @ W[26-k]
                pairs[3 * idx + 0] = rank_[i];
                pairs[3 * idx + 1] = j;
                pairs[3 * idx + 2] = k;
                pairs[3 * idx + 3] = rank_[j];
                pairs[3 * idx + 4] = i;
                pairs[3 * idx + 5] = 26 - k;
            }
        }
    }
}

// K7: sparse pairs — one wave per pair, fp32 shuffle-dot, atomic accumulate.
__global__ void k_pairs(const float* __restrict__ feat, const float* __restrict__ kern,
                        const int* __restrict__ pairs, const int* __restrict__ paircnt,
                        float* __restrict__ out) {
    int gtid = blockIdx.x * blockDim.x + threadIdx.x;
    int wid = gtid >> 6, lane = gtid & 63;
    int nw = (gridDim.x * blockDim.x) >> 6;
    int cnt = *paircnt;
    if (cnt > PAIR_CAP) cnt = PAIR_CAP;
    for (int p = wid; p < cnt; p += nw) {
        int dst = pairs[3 * p], src = pairs[3 * p + 1], wk = pairs[3 * p + 2];
        float f = feat[(size_t)src * 64 + lane];
        const float* W = kern + wk * 4096;
        float acc = 0.f;
#pragma unroll
        for (int c = 0; c < 64; ++c)
            acc += __shfl(f, c, 64) * W[c * 64 + lane];
        atomicAdd(&out[(size_t)dst * 64 + lane], acc);
    }
}

extern "C" void kernel_launch(void* const* d_in, const int* in_sizes, int n_in,
                              void* d_out, int out_size, void* d_ws, size_t ws_size,
                              hipStream_t stream) {
    const float* feat   = (const float*)d_in[0];
    const float* kern   = (const float*)d_in[1];
    const int*   coords = (const int*)d_in[2];
    const int*   offs   = (const int*)d_in[3];
    float* out = (float*)d_out;
    int N = in_sizes[0] / 64;

    // ---- workspace layout (256B-aligned slabs) ----
    char* w = (char*)d_ws;
    auto alloc = [&](size_t bytes) { char* p = w; w += (bytes + 255) & ~(size_t)255; return p; };
    int* keys    = (int*)alloc((size_t)N * 4);
    int* bkeys   = (int*)alloc((size_t)N * 4);
    int* borig   = (int*)alloc((size_t)N * 4);
    int* sorder  = (int*)alloc((size_t)N * 4);
    int* rank_   = (int*)alloc((size_t)N * 4);
    int* hist    = (int*)alloc(4096 * 4);        // contiguous: hist, cnt, paircnt
    int* cnt     = (int*)alloc(4096 * 4);
    int* paircnt = (int*)alloc(256);
    int* base    = (int*)alloc(4097 * 4);
    int* hkeys   = (int*)alloc((size_t)HSIZE * 4);
    int* hvals   = (int*)alloc((size_t)HSIZE * 4);
    int* pairs   = (int*)alloc((size_t)PAIR_CAP * 12);
    bf16_t* wf   = (bf16_t*)alloc(4096 * 2);

    // zero hist+cnt+paircnt (contiguous slabs); hash keys -> -1
    hipMemsetAsync(hist, 0, 4096 * 4 + 4096 * 4 + 256, stream);
    hipMemsetAsync(hkeys, 0xFF, (size_t)HSIZE * 4, stream);

    int nb = (N + 255) / 256;
    k_phase1  <<<nb + 16, 256, 0, stream>>>(coords, kern, keys, hist, wf, N, nb);
    k_prefix  <<<1, 256, 0, stream>>>(hist, base);
    k_build   <<<nb, 256, 0, stream>>>(keys, base, cnt, bkeys, borig, hkeys, hvals, N);
    k_sortrank<<<4096, 256, 0, stream>>>(base, bkeys, borig, sorder, rank_);
    k_gemm    <<<(N + 63) / 64, 256, 0, stream>>>(feat, wf, sorder, out, N);
    k_query   <<<nb, 256, 0, stream>>>(keys, rank_, offs, hkeys, hvals, paircnt, pairs, N);
    k_pairs   <<<256, 256, 0, stream>>>(feat, kern, pairs, paircnt, out);
}